// Round 12
// baseline (272.598 us; speedup 1.0000x reference)
//
#include <hip/hip_runtime.h>
#include <math.h>

#define GAS __attribute__((address_space(1)))
#define LAS __attribute__((address_space(3)))

typedef __attribute__((ext_vector_type(4))) float f32x4;
typedef __attribute__((ext_vector_type(8))) short bf16x8;
typedef __attribute__((ext_vector_type(4))) short bf16x4;

#define MFMA(a,b,c)   __builtin_amdgcn_mfma_f32_16x16x32_bf16((a),(b),(c),0,0,0)
#define MFMA16(a,b,c) __builtin_amdgcn_mfma_f32_16x16x16bf16_1k((a),(b),(c),0,0,0)

#if __has_builtin(__builtin_amdgcn_exp2f)
#define EXP2(x) __builtin_amdgcn_exp2f(x)
#else
#define EXP2(x) exp2f(x)
#endif

__device__ __forceinline__ void gl_lds16(const void* g, void* l) {
    __builtin_amdgcn_global_load_lds((const GAS unsigned*)g, (LAS unsigned*)l, 16, 0, 0);
}

__device__ __forceinline__ short f2bf(float f) {
    union { float f; unsigned u; } v; v.f = f;
    unsigned r = (v.u + 0x7fff + ((v.u >> 16) & 1)) >> 16;   // RNE
    return (short)r;
}

__device__ __forceinline__ void castN(const float* __restrict__ s, short* __restrict__ d,
                                      int n4, int gid, int gsz) {
    for (int i = gid; i < n4; i += gsz) {
        float4 v = ((const float4*)s)[i];
        short4 o = make_short4(f2bf(v.x), f2bf(v.y), f2bf(v.z), f2bf(v.w));
        ((short4*)d)[i] = o;
    }
}

__global__ __launch_bounds__(256)
void cast_all(const float* __restrict__ x,  const float* __restrict__ wq,
              const float* __restrict__ wk, const float* __restrict__ wv,
              const float* __restrict__ wo,
              short* __restrict__ xb, short* __restrict__ wqkv, short* __restrict__ wob) {
    int gid = blockIdx.x*256 + threadIdx.x;
    int gsz = gridDim.x*256;
    castN(x,  xb,               (4096*2048)/4, gid, gsz);
    castN(wq, wqkv,             (2048*2048)/4, gid, gsz);
    castN(wk, wqkv + 2048*2048, (512*2048)/4,  gid, gsz);
    castN(wv, wqkv + 2560*2048, (512*2048)/4,  gid, gsz);
    castN(wo, wob,              (2048*2048)/4, gid, gsz);
}

// 128M x BN-tile bf16 MFMA GEMM, 8-wave blocks: C(M,N) = A(M,K) @ Bw(N,K)^T.
// 512 thr = 8 waves (2M x 4N), per-wave 64 x (BN/4) output (acc 4 x BN/64).
// BK=32 phases, 3-slot LDS ring, stage-ahead 2, counted vmcnt (never drain-to-0
// until tail). Conflict-free LDS: 16B-chunk XOR swizzle on pre-swizzled GLOBAL
// source + ds_read addr (0 conflicts measured r5-r11).
// BN=128 (Wo): slot 8 KB, 24 KB total -> 3 blocks/CU, acc 4x2. Measured r7:
//   73.5 us, MfmaUtil 28.8 -- but LDS-read/MFMA = 0.75 KB (binding pipe).
// BN=256 (QKV): slot 24 KB, 72 KB total -> 2 blocks/CU (16 waves), acc 4x4 ->
//   LDS-read/MFMA = 0.5 KB; per-instance MFMA 620 cyc vs LDS 500-750 cyc
//   (balanced, was LDS-dominated). r12 experiment.
// MODE 0: fp32 row-major to Cf (Wo path).
// MODE 1: fused QKV epilogue: RoPE via shfl_xor(1) + bf16 stores; Q pre-scaled by
//         0.125*log2e; V stored TRANSPOSED (B,8,64d,1024t).
template<int MODE, int BN>
__global__ __launch_bounds__(512, (BN == 256) ? 4 : 6)
void gemm_mfma(const short* __restrict__ A, const short* __restrict__ Bw,
               int M, int N, int K, float* __restrict__ Cf,
               short* __restrict__ qo, short* __restrict__ ko, short* __restrict__ vo,
               const float* __restrict__ cosb, const float* __restrict__ sinb)
{
    constexpr int JN = BN / 64;            // N-fragments per wave (2 or 4)
    __shared__ short smem[12288 + 96*BN];  // A 3x4096 | B 3x(BN*32)

    const int tid  = threadIdx.x;
    const int lane = tid & 63, wvi = tid >> 6;        // 8 waves
    const int l15  = lane & 15, quad = lane >> 4;
    const int wm   = wvi >> 2,  wn   = wvi & 3;       // 2M x 4N
    const int m0   = blockIdx.y * 128, n0 = blockIdx.x * BN;

    // staging: row = base + (lane>>2), fetched 16B chunk pre-swizzled
    const int srow   = lane >> 2;
    const int schunk = ((lane & 3) ^ ((lane >> 3) & 3)) << 3;
    const short* gA = A  + (size_t)(m0 + wvi*16 + srow)*K + schunk;
    const short* gB = Bw + (size_t)(n0 + wvi*(BN/8) + srow)*K + schunk;

    // fragment-read offsets (swizzled), in shorts
    const int swz  = (quad ^ ((l15 >> 1) & 3)) << 3;
    const int ard  = (wm*64 + l15)*32 + swz;               // + i*512 + slotA*4096
    const int brd  = 12288 + (wn*(16*JN) + l15)*32 + swz;  // + j*512 + slotB*BN*32

    f32x4 acc[4][JN] = {};

#define SBAR  __builtin_amdgcn_s_barrier()
#define PRIO1 __builtin_amdgcn_s_setprio(1)
#define PRIO0 __builtin_amdgcn_s_setprio(0)
#define VMW(n) asm volatile("s_waitcnt vmcnt(" #n ")" ::: "memory")

#define STG(h, s) do { const int _k = (h)<<5;                                      \
    gl_lds16(gA + _k, &smem[(s)*4096 + wvi*512]);                                  \
    gl_lds16(gB + _k, &smem[12288 + (s)*(BN*32) + wvi*(BN*4)]);                    \
    if (BN == 256)                                                                 \
        gl_lds16(gB + (size_t)16*K + _k,                                           \
                 &smem[12288 + (s)*(BN*32) + wvi*(BN*4) + 512]);                   \
} while(0)
// loads per STG: 1 + BN/128  ->  VMW_N = that count (stage-ahead 2 in flight)
#define VMW_CNT do { if (BN == 256) { VMW(3); } else { VMW(2); } } while(0)

    const int H = K >> 5;            // 64 phases (K=2048)

    STG(0, 0); STG(1, 1);
    VMW_CNT; SBAR;

    int sc = 0;                       // slot of phase h
    for (int h = 0; h < H; ++h) {
        bf16x8 a[4], b[JN];
        const int sa = sc*4096, sb = sc*(BN*32);
        #pragma unroll
        for (int i = 0; i < 4; i++)  a[i] = *(const bf16x8*)&smem[sa + ard + i*512];
        #pragma unroll
        for (int j = 0; j < JN; j++) b[j] = *(const bf16x8*)&smem[sb + brd + j*512];

        if (h + 2 < H) {              // stage phase h+2 into the slot being retired
            int s2 = sc + 2; if (s2 >= 3) s2 -= 3;
            STG(h + 2, s2);
        }

        PRIO1;
        #pragma unroll
        for (int i = 0; i < 4; i++)
            #pragma unroll
            for (int j = 0; j < JN; j++) acc[i][j] = MFMA(a[i], b[j], acc[i][j]);
        PRIO0;

        if (h + 2 < H)      { VMW_CNT; }
        else if (h + 1 < H) { VMW(0); }
        SBAR;
        sc = (sc == 2) ? 0 : sc + 1;
    }
#undef STG
#undef VMW
#undef VMW_CNT

    if (MODE == 0) {
        #pragma unroll
        for (int i = 0; i < 4; i++)
            #pragma unroll
            for (int j = 0; j < JN; j++) {
                int n  = n0 + wn*(16*JN) + j*16 + l15;
                int mb = m0 + wm*64 + i*16 + quad*4;
                #pragma unroll
                for (int r = 0; r < 4; r++)
                    Cf[(size_t)(mb + r)*N + n] = acc[i][j][r];
            }
    } else {
        #pragma unroll
        for (int i = 0; i < 4; i++)
            #pragma unroll
            for (int j = 0; j < JN; j++) {
                int n  = n0 + wn*(16*JN) + j*16 + l15;  // 16-range stays in one 64-block
                int mb = m0 + wm*64 + i*16 + quad*4;
                if (n >= 2560) {                     // V: transposed store, 4 consecutive t
                    int bq = mb >> 10, t0 = mb & 1023;
                    int hv = (n - 2560) >> 6, d = (n - 2560) & 63;
                    short4 s4 = make_short4(f2bf(acc[i][j][0]), f2bf(acc[i][j][1]),
                                            f2bf(acc[i][j][2]), f2bf(acc[i][j][3]));
                    *(short4*)&vo[(((size_t)(bq*8 + hv)*64 + d) << 10) + t0] = s4;
                } else {
                    #pragma unroll
                    for (int r = 0; r < 4; r++) {
                        int m = mb + r;
                        int b = m >> 10, t = m & 1023;
                        float val = acc[i][j][r];
                        float part = __shfl_xor(val, 1);
                        int d2 = (n & 63) >> 1;
                        float c = cosb[t*32 + d2], s = sinb[t*32 + d2];
                        val = (n & 1) ? (part*s + val*c) : (val*c - part*s);
                        if (n < 2048) {
                            val *= 0.18033688f;      // 64^-0.5 * log2(e)
                            qo[(((size_t)(b*32 + (n>>6))*1024 + t) << 6) + (n & 63)] = f2bf(val);
                        } else {
                            ko[(((size_t)(b*8 + ((n-2048)>>6))*1024 + t) << 6) + ((n-2048) & 63)] = f2bf(val);
                        }
                    }
                }
            }
    }
}

// GQA-fused MFMA flash attention (r11 config, best measured: total 261.6).
// Block = (b, kvh, qtile) = 1024 thr = 16 waves = 4 q-heads x 4 row-groups;
// K/V staged ONCE per block (4-head reuse), double-buffered, ONE barrier per
// 64-key chunk. Transposed-S: S^T = K Q^T feeds O^T = V^T P^T in-register.
// launch_bounds(1024,8): 64-VGPR waves -> 2 blocks/CU, all 512 blocks resident.
// KVBLK=64 is the ceiling at this reg cap (r10: 128 spilled -> 280 MB scratch).
// qt = (z&2) ? bx : 15-bx -> co-resident pairs sum to 17 chunks (r6: -15 us).
// s_setprio(1) around QK^T/PV MFMA clusters (T5; r11 kept it).
__global__ __launch_bounds__(1024, 8)
void attn_mfma(const short* __restrict__ q_ws, const short* __restrict__ k_ws,
               const short* __restrict__ vt_ws, short* __restrict__ o_ws)
{
    __shared__ short Ks[2][4096];     // [kc2][64k][32d]
    __shared__ short Vs[2][4608];     // [64d][64key] stride 72

    const int tid = threadIdx.x, lane = tid & 63, wv = tid >> 6;
    const int qt = (blockIdx.z & 2) ? blockIdx.x : (15 - blockIdx.x);
    const int kvh = blockIdx.y, b = blockIdx.z;
    const int hq = wv & 3, rgrp = wv >> 2;
    const int head = kvh*4 + hq;
    const size_t qbase  = ((size_t)(b*32 + head)) << 16;
    const size_t kvbase = ((size_t)(b*8  + kvh )) << 16;
    const short* kt = k_ws  + kvbase;
    const short* vt = vt_ws + kvbase;
    const int l15 = lane & 15, quad = lane >> 4;

    // staging roles
    const bool vstager = (tid < 512);
    const int vrow = tid >> 3, vcol = (tid & 7)*8;           // tid<512: V row d, key chunk
    const int g = tid & 511;                                  // tid>=512: K linear slot
    const int kc = g >> 8, kr = (g >> 2) & 63, dq = (g & 3)*8;

    // chunk 0
    if (vstager) {
        bf16x8 v0 = *(const bf16x8*)(vt + (size_t)vrow*1024 + vcol);
        *(bf16x8*)&Vs[0][vrow*72 + vcol] = v0;
    } else {
        gl_lds16(kt + (size_t)kr*64 + kc*32 + dq, &Ks[0][(wv - 8)*512]);
    }

    // Q B-fragments direct from global (once)
    const short* qp = q_ws + qbase + (size_t)(qt*64 + rgrp*16 + l15)*64 + quad*8;
    bf16x8 aq0 = *(const bf16x8*)qp;
    bf16x8 aq1 = *(const bf16x8*)(qp + 32);

    f32x4 o_acc[4] = {};                          // O^T: row d=quad*4+r (+16dt), col q=l15
    float lsum = 0.f;
    const int qrel = rgrp*16 + l15;

    for (int c = 0; c <= qt; c++) {
        const int cb = c & 1, nb = cb ^ 1;
        __syncthreads();                          // K[c]/V[c] visible; prev reads done
        bf16x8 vreg;
        const bool pre = (c < qt);
        if (pre) {                                // prefetch chunk c+1
            if (vstager)
                vreg = *(const bf16x8*)(vt + (size_t)vrow*1024 + (c+1)*64 + vcol);
            else
                gl_lds16(kt + (size_t)((c+1)*64 + kr)*64 + kc*32 + dq,
                         &Ks[nb][(wv - 8)*512]);
        }

        // S^T = K Q^T  (log2 domain, Q pre-scaled)
        f32x4 s_acc[4];
        __builtin_amdgcn_s_setprio(1);
        #pragma unroll
        for (int nt = 0; nt < 4; nt++) {
            bf16x8 kf0 = *(const bf16x8*)&Ks[cb][(nt*16 + l15)*32 + quad*8];
            bf16x8 kf1 = *(const bf16x8*)&Ks[cb][2048 + (nt*16 + l15)*32 + quad*8];
            f32x4 z = {};
            z = MFMA(kf0, aq0, z);
            s_acc[nt] = MFMA(kf1, aq1, z);
        }
        __builtin_amdgcn_s_setprio(0);

        // shift-free softmax numerators; in-register C->B transform
        bf16x4 pb[4];
        if (c == qt) {                            // diagonal chunk only: causal mask
            #pragma unroll
            for (int nt = 0; nt < 4; nt++)
                #pragma unroll
                for (int r = 0; r < 4; r++) {
                    float p = (nt*16 + quad*4 + r > qrel) ? 0.f : EXP2(s_acc[nt][r]);
                    lsum += p;
                    pb[nt][r] = f2bf(p);
                }
        } else {
            #pragma unroll
            for (int nt = 0; nt < 4; nt++)
                #pragma unroll
                for (int r = 0; r < 4; r++) {
                    float p = EXP2(s_acc[nt][r]);
                    lsum += p;
                    pb[nt][r] = f2bf(p);
                }
        }

        if (pre && vstager)                       // V regs -> LDS (latency now hidden)
            *(bf16x8*)&Vs[nb][vrow*72 + vcol] = vreg;

        // O^T += V^T P^T
        __builtin_amdgcn_s_setprio(1);
        #pragma unroll
        for (int dt = 0; dt < 4; dt++)
            #pragma unroll
            for (int nt = 0; nt < 4; nt++) {
                bf16x4 vf = *(const bf16x4*)&Vs[cb][(dt*16 + l15)*72 + nt*16 + quad*4];
                o_acc[dt] = MFMA16(vf, pb[nt], o_acc[dt]);
            }
        __builtin_amdgcn_s_setprio(0);
    }

    lsum += __shfl_xor(lsum, 16);                 // combine the 4 quads of this q
    lsum += __shfl_xor(lsum, 32);
    float inv = 1.f / lsum;
    short* orow = o_ws + ((size_t)(b*1024 + qt*64 + qrel))*2048 + head*64;
    #pragma unroll
    for (int dt = 0; dt < 4; dt++) {
        short4 s4 = make_short4(f2bf(o_acc[dt][0]*inv), f2bf(o_acc[dt][1]*inv),
                                f2bf(o_acc[dt][2]*inv), f2bf(o_acc[dt][3]*inv));
        *(short4*)&orow[dt*16 + quad*4] = s4;
    }
}

extern "C" void kernel_launch(void* const* d_in, const int* in_sizes, int n_in,
                              void* d_out, int out_size, void* d_ws, size_t ws_size,
                              hipStream_t stream) {
    const float* x    = (const float*)d_in[0];
    const float* cosb = (const float*)d_in[1];
    const float* sinb = (const float*)d_in[2];
    const float* Wq   = (const float*)d_in[3];
    const float* Wk   = (const float*)d_in[4];
    const float* Wv   = (const float*)d_in[5];
    const float* Wo   = (const float*)d_in[6];
    float* out = (float*)d_out;

    short* xb   = (short*)d_ws;          // 8,388,608
    short* wqkv = xb   + 8388608;        // 6,291,456  [Wq;Wk;Wv] (3072,2048)
    short* wob  = wqkv + 6291456;        // 4,194,304
    short* q_ws = wob  + 4194304;        // 8,388,608  (B,32,T,64)  pre-scaled
    short* k_ws = q_ws + 8388608;        // 2,097,152  (B,8,T,64)
    short* v_ws = k_ws + 2097152;        // 2,097,152  (B,8,64,T)  TRANSPOSED
    short* o_ws = v_ws + 2097152;        // 8,388,608  (B,T,2048)

    cast_all<<<2048, 256, 0, stream>>>(x, Wq, Wk, Wv, Wo, xb, wqkv, wob);
    gemm_mfma<1, 256><<<dim3(12, 32), 512, 0, stream>>>(xb, wqkv, 4096, 3072, 2048,
                                                        nullptr, q_ws, k_ws, v_ws, cosb, sinb);
    attn_mfma<<<dim3(16, 8, 4), 1024, 0, stream>>>(q_ws, k_ws, v_ws, o_ws);
    gemm_mfma<0, 128><<<dim3(16, 32), 512, 0, stream>>>(o_ws, wob, 4096, 2048, 2048,
                                                        out, nullptr, nullptr, nullptr, nullptr, nullptr);
}

// Round 15
// 260.023 us; speedup vs baseline: 1.0484x; 1.0484x over previous
//
#include <hip/hip_runtime.h>
#include <math.h>

#define GAS __attribute__((address_space(1)))
#define LAS __attribute__((address_space(3)))

typedef __attribute__((ext_vector_type(4))) float f32x4;
typedef __attribute__((ext_vector_type(8))) short bf16x8;
typedef __attribute__((ext_vector_type(4))) short bf16x4;

#define MFMA(a,b,c)   __builtin_amdgcn_mfma_f32_16x16x32_bf16((a),(b),(c),0,0,0)
#define MFMA16(a,b,c) __builtin_amdgcn_mfma_f32_16x16x16bf16_1k((a),(b),(c),0,0,0)

#if __has_builtin(__builtin_amdgcn_exp2f)
#define EXP2(x) __builtin_amdgcn_exp2f(x)
#else
#define EXP2(x) exp2f(x)
#endif

__device__ __forceinline__ void gl_lds16(const void* g, void* l) {
    __builtin_amdgcn_global_load_lds((const GAS unsigned*)g, (LAS unsigned*)l, 16, 0, 0);
}

__device__ __forceinline__ short f2bf(float f) {
    union { float f; unsigned u; } v; v.f = f;
    unsigned r = (v.u + 0x7fff + ((v.u >> 16) & 1)) >> 16;   // RNE
    return (short)r;
}

__device__ __forceinline__ void castN(const float* __restrict__ s, short* __restrict__ d,
                                      int n4, int gid, int gsz) {
    for (int i = gid; i < n4; i += gsz) {
        float4 v = ((const float4*)s)[i];
        short4 o = make_short4(f2bf(v.x), f2bf(v.y), f2bf(v.z), f2bf(v.w));
        ((short4*)d)[i] = o;
    }
}

__global__ __launch_bounds__(256)
void cast_all(const float* __restrict__ x,  const float* __restrict__ wq,
              const float* __restrict__ wk, const float* __restrict__ wv,
              const float* __restrict__ wo,
              short* __restrict__ xb, short* __restrict__ wqkv, short* __restrict__ wob) {
    int gid = blockIdx.x*256 + threadIdx.x;
    int gsz = gridDim.x*256;
    castN(x,  xb,               (4096*2048)/4, gid, gsz);
    castN(wq, wqkv,             (2048*2048)/4, gid, gsz);
    castN(wk, wqkv + 2048*2048, (512*2048)/4,  gid, gsz);
    castN(wv, wqkv + 2560*2048, (512*2048)/4,  gid, gsz);
    castN(wo, wob,              (2048*2048)/4, gid, gsz);
}

// 128x128-tile bf16 MFMA GEMM, 8-WAVE blocks: C(M,N) = A(M,K) @ Bw(N,K)^T.
// 512 thr = 8 waves (2M x 4N), per-wave 64x32 output (acc 4x2), BK=32 phases.
// 3-slot LDS ring (48 KiB -> 3 blocks/CU = 24 waves/CU), stage-ahead 2, counted
// vmcnt(2) (never drain-to-0 until tail). Conflict-free LDS: 16B-chunk XOR
// swizzle on pre-swizzled GLOBAL source + ds_read addr (0 conflicts, r5-r12).
// Measured r7/r11: QKV 73.5-74.7 us, MfmaUtil ~29, occupancy ~51%.
// PLATEAU NOTE (r12/r13): 8 structural variants (tile 128/256, 4/8 waves,
// 2-phase/8-phase/ring, BN=256, split-K) all land QKV 73-86 us; MfmaUtil
// pinned ~29% independent of LDS-read ratio and wave count. Structural ceiling
// for this family at HIP source level; split-K abandoned (r13/r14 container
// failures, suspected atomics/zero-fill interaction with harness).
// MODE 0: fp32 row-major to Cf (Wo path).
// MODE 1: fused QKV epilogue: RoPE via shfl_xor(1) + bf16 stores; Q pre-scaled by
//         0.125*log2e; V stored TRANSPOSED (B,8,64d,1024t).
template<int MODE>
__global__ __launch_bounds__(512, 6)
void gemm_mfma(const short* __restrict__ A, const short* __restrict__ Bw,
               int M, int N, int K, float* __restrict__ Cf,
               short* __restrict__ qo, short* __restrict__ ko, short* __restrict__ vo,
               const float* __restrict__ cosb, const float* __restrict__ sinb)
{
    __shared__ short smem[24576];   // 48 KiB: 3 slots x (A[128][32] | B[128][32])

    const int tid  = threadIdx.x;
    const int lane = tid & 63, wvi = tid >> 6;        // 8 waves
    const int l15  = lane & 15, quad = lane >> 4;
    const int wm   = wvi >> 2,  wn   = wvi & 3;       // 2M x 4N
    const int m0   = blockIdx.y * 128, n0 = blockIdx.x * 128;

    const int srow   = lane >> 2;
    const int schunk = ((lane & 3) ^ ((lane >> 3) & 3)) << 3;
    const short* gA = A  + (size_t)(m0 + wvi*16 + srow)*K + schunk;
    const short* gB = Bw + (size_t)(n0 + wvi*16 + srow)*K + schunk;

    const int swz     = (quad ^ ((l15 >> 1) & 3)) << 3;
    const int ardbase = (wm*64 + l15)*32 + swz;            // + mi*512
    const int brdbase = 4096 + (wn*32 + l15)*32 + swz;     // + nj*512

    f32x4 acc[4][2] = {};

#define SBAR  __builtin_amdgcn_s_barrier()
#define PRIO1 __builtin_amdgcn_s_setprio(1)
#define PRIO0 __builtin_amdgcn_s_setprio(0)
#define VMW(n) asm volatile("s_waitcnt vmcnt(" #n ")" ::: "memory")

#define STG(h, s) do { const int _k = (h)<<5;                                      \
    gl_lds16(gA + _k,  &smem[(s)*8192 + wvi*512]);                                 \
    gl_lds16(gB + _k,  &smem[(s)*8192 + 4096 + wvi*512]);                          \
} while(0)

    const int H = K >> 5;            // 64 phases (K=2048)

    STG(0, 0); STG(1, 1);
    VMW(2); SBAR;

    int sc = 0;                       // slot of phase h
    for (int h = 0; h < H; ++h) {
        bf16x8 a[4], b[2];
        const int sb = sc*8192;
        #pragma unroll
        for (int i = 0; i < 4; i++) a[i] = *(const bf16x8*)&smem[sb + ardbase + i*512];
        #pragma unroll
        for (int j = 0; j < 2; j++) b[j] = *(const bf16x8*)&smem[sb + brdbase + j*512];

        if (h + 2 < H) {              // stage phase h+2 into the slot being retired
            int s2 = sc + 2; if (s2 >= 3) s2 -= 3;
            STG(h + 2, s2);
        }

        PRIO1;
        #pragma unroll
        for (int i = 0; i < 4; i++)
            #pragma unroll
            for (int j = 0; j < 2; j++) acc[i][j] = MFMA(a[i], b[j], acc[i][j]);
        PRIO0;

        if (h + 2 < H)      { VMW(2); }
        else if (h + 1 < H) { VMW(0); }
        SBAR;
        sc = (sc == 2) ? 0 : sc + 1;
    }
#undef STG
#undef VMW

    if (MODE == 0) {
        #pragma unroll
        for (int i = 0; i < 4; i++)
            #pragma unroll
            for (int j = 0; j < 2; j++) {
                int n  = n0 + wn*32 + j*16 + l15;
                int mb = m0 + wm*64 + i*16 + quad*4;
                #pragma unroll
                for (int r = 0; r < 4; r++)
                    Cf[(size_t)(mb + r)*N + n] = acc[i][j][r];
            }
    } else {
        #pragma unroll
        for (int i = 0; i < 4; i++)
            #pragma unroll
            for (int j = 0; j < 2; j++) {
                int n  = n0 + wn*32 + j*16 + l15;   // 16-range never crosses a 64-boundary
                int mb = m0 + wm*64 + i*16 + quad*4;
                if (n >= 2560) {                     // V: transposed store, 4 consecutive t
                    int bq = mb >> 10, t0 = mb & 1023;
                    int hv = (n - 2560) >> 6, d = (n - 2560) & 63;
                    short4 s4 = make_short4(f2bf(acc[i][j][0]), f2bf(acc[i][j][1]),
                                            f2bf(acc[i][j][2]), f2bf(acc[i][j][3]));
                    *(short4*)&vo[(((size_t)(bq*8 + hv)*64 + d) << 10) + t0] = s4;
                } else {
                    #pragma unroll
                    for (int r = 0; r < 4; r++) {
                        int m = mb + r;
                        int b = m >> 10, t = m & 1023;
                        float val = acc[i][j][r];
                        float part = __shfl_xor(val, 1);
                        int d2 = (n & 63) >> 1;
                        float c = cosb[t*32 + d2], s = sinb[t*32 + d2];
                        val = (n & 1) ? (part*s + val*c) : (val*c - part*s);
                        if (n < 2048) {
                            val *= 0.18033688f;      // 64^-0.5 * log2(e)
                            qo[(((size_t)(b*32 + (n>>6))*1024 + t) << 6) + (n & 63)] = f2bf(val);
                        } else {
                            ko[(((size_t)(b*8 + ((n-2048)>>6))*1024 + t) << 6) + ((n-2048) & 63)] = f2bf(val);
                        }
                    }
                }
            }
    }
}

// GQA-fused MFMA flash attention (r11 config, best measured: total 261.6).
// Block = (b, kvh, qtile) = 1024 thr = 16 waves = 4 q-heads x 4 row-groups;
// K/V staged ONCE per block (4-head reuse), double-buffered, ONE barrier per
// 64-key chunk. Transposed-S: S^T = K Q^T feeds O^T = V^T P^T in-register.
// launch_bounds(1024,8): 64-VGPR waves -> 2 blocks/CU, all 512 blocks resident.
// KVBLK=64 is the ceiling at this reg cap (r10: 128 spilled -> 280 MB scratch).
// qt = (z&2) ? bx : 15-bx -> co-resident pairs sum to 17 chunks (r6: -15 us).
// s_setprio(1) around QK^T/PV MFMA clusters (T5; r11 kept it).
__global__ __launch_bounds__(1024, 8)
void attn_mfma(const short* __restrict__ q_ws, const short* __restrict__ k_ws,
               const short* __restrict__ vt_ws, short* __restrict__ o_ws)
{
    __shared__ short Ks[2][4096];     // [kc2][64k][32d]
    __shared__ short Vs[2][4608];     // [64d][64key] stride 72

    const int tid = threadIdx.x, lane = tid & 63, wv = tid >> 6;
    const int qt = (blockIdx.z & 2) ? blockIdx.x : (15 - blockIdx.x);
    const int kvh = blockIdx.y, b = blockIdx.z;
    const int hq = wv & 3, rgrp = wv >> 2;
    const int head = kvh*4 + hq;
    const size_t qbase  = ((size_t)(b*32 + head)) << 16;
    const size_t kvbase = ((size_t)(b*8  + kvh )) << 16;
    const short* kt = k_ws  + kvbase;
    const short* vt = vt_ws + kvbase;
    const int l15 = lane & 15, quad = lane >> 4;

    // staging roles
    const bool vstager = (tid < 512);
    const int vrow = tid >> 3, vcol = (tid & 7)*8;           // tid<512: V row d, key chunk
    const int g = tid & 511;                                  // tid>=512: K linear slot
    const int kc = g >> 8, kr = (g >> 2) & 63, dq = (g & 3)*8;

    // chunk 0
    if (vstager) {
        bf16x8 v0 = *(const bf16x8*)(vt + (size_t)vrow*1024 + vcol);
        *(bf16x8*)&Vs[0][vrow*72 + vcol] = v0;
    } else {
        gl_lds16(kt + (size_t)kr*64 + kc*32 + dq, &Ks[0][(wv - 8)*512]);
    }

    // Q B-fragments direct from global (once)
    const short* qp = q_ws + qbase + (size_t)(qt*64 + rgrp*16 + l15)*64 + quad*8;
    bf16x8 aq0 = *(const bf16x8*)qp;
    bf16x8 aq1 = *(const bf16x8*)(qp + 32);

    f32x4 o_acc[4] = {};                          // O^T: row d=quad*4+r (+16dt), col q=l15
    float lsum = 0.f;
    const int qrel = rgrp*16 + l15;

    for (int c = 0; c <= qt; c++) {
        const int cb = c & 1, nb = cb ^ 1;
        __syncthreads();                          // K[c]/V[c] visible; prev reads done
        bf16x8 vreg;
        const bool pre = (c < qt);
        if (pre) {                                // prefetch chunk c+1
            if (vstager)
                vreg = *(const bf16x8*)(vt + (size_t)vrow*1024 + (c+1)*64 + vcol);
            else
                gl_lds16(kt + (size_t)((c+1)*64 + kr)*64 + kc*32 + dq,
                         &Ks[nb][(wv - 8)*512]);
        }

        // S^T = K Q^T  (log2 domain, Q pre-scaled)
        f32x4 s_acc[4];
        __builtin_amdgcn_s_setprio(1);
        #pragma unroll
        for (int nt = 0; nt < 4; nt++) {
            bf16x8 kf0 = *(const bf16x8*)&Ks[cb][(nt*16 + l15)*32 + quad*8];
            bf16x8 kf1 = *(const bf16x8*)&Ks[cb][2048 + (nt*16 + l15)*32 + quad*8];
            f32x4 z = {};
            z = MFMA(kf0, aq0, z);
            s_acc[nt] = MFMA(kf1, aq1, z);
        }
        __builtin_amdgcn_s_setprio(0);

        // shift-free softmax numerators; in-register C->B transform
        bf16x4 pb[4];
        if (c == qt) {                            // diagonal chunk only: causal mask
            #pragma unroll
            for (int nt = 0; nt < 4; nt++)
                #pragma unroll
                for (int r = 0; r < 4; r++) {
                    float p = (nt*16 + quad*4 + r > qrel) ? 0.f : EXP2(s_acc[nt][r]);
                    lsum += p;
                    pb[nt][r] = f2bf(p);
                }
        } else {
            #pragma unroll
            for (int nt = 0; nt < 4; nt++)
                #pragma unroll
                for (int r = 0; r < 4; r++) {
                    float p = EXP2(s_acc[nt][r]);
                    lsum += p;
                    pb[nt][r] = f2bf(p);
                }
        }

        if (pre && vstager)                       // V regs -> LDS (latency now hidden)
            *(bf16x8*)&Vs[nb][vrow*72 + vcol] = vreg;

        // O^T += V^T P^T
        __builtin_amdgcn_s_setprio(1);
        #pragma unroll
        for (int dt = 0; dt < 4; dt++)
            #pragma unroll
            for (int nt = 0; nt < 4; nt++) {
                bf16x4 vf = *(const bf16x4*)&Vs[cb][(dt*16 + l15)*72 + nt*16 + quad*4];
                o_acc[dt] = MFMA16(vf, pb[nt], o_acc[dt]);
            }
        __builtin_amdgcn_s_setprio(0);
    }

    lsum += __shfl_xor(lsum, 16);                 // combine the 4 quads of this q
    lsum += __shfl_xor(lsum, 32);
    float inv = 1.f / lsum;
    short* orow = o_ws + ((size_t)(b*1024 + qt*64 + qrel))*2048 + head*64;
    #pragma unroll
    for (int dt = 0; dt < 4; dt++) {
        short4 s4 = make_short4(f2bf(o_acc[dt][0]*inv), f2bf(o_acc[dt][1]*inv),
                                f2bf(o_acc[dt][2]*inv), f2bf(o_acc[dt][3]*inv));
        *(short4*)&orow[dt*16 + quad*4] = s4;
    }
}

extern "C" void kernel_launch(void* const* d_in, const int* in_sizes, int n_in,
                              void* d_out, int out_size, void* d_ws, size_t ws_size,
                              hipStream_t stream) {
    const float* x    = (const float*)d_in[0];
    const float* cosb = (const float*)d_in[1];
    const float* sinb = (const float*)d_in[2];
    const float* Wq   = (const float*)d_in[3];
    const float* Wk   = (const float*)d_in[4];
    const float* Wv   = (const float*)d_in[5];
    const float* Wo   = (const float*)d_in[6];
    float* out = (float*)d_out;

    short* xb   = (short*)d_ws;          // 8,388,608
    short* wqkv = xb   + 8388608;        // 6,291,456  [Wq;Wk;Wv] (3072,2048)
    short* wob  = wqkv + 6291456;        // 4,194,304
    short* q_ws = wob  + 4194304;        // 8,388,608  (B,32,T,64)  pre-scaled
    short* k_ws = q_ws + 8388608;        // 2,097,152  (B,8,T,64)
    short* v_ws = k_ws + 2097152;        // 2,097,152  (B,8,64,T)  TRANSPOSED
    short* o_ws = v_ws + 2097152;        // 8,388,608  (B,T,2048)

    cast_all<<<2048, 256, 0, stream>>>(x, Wq, Wk, Wv, Wo, xb, wqkv, wob);
    gemm_mfma<1><<<dim3(24, 32), 512, 0, stream>>>(xb, wqkv, 4096, 3072, 2048,
                                                   nullptr, q_ws, k_ws, v_ws, cosb, sinb);
    attn_mfma<<<dim3(16, 8, 4), 1024, 0, stream>>>(q_ws, k_ws, v_ws, o_ws);
    gemm_mfma<0><<<dim3(16, 32), 512, 0, stream>>>(o_ws, wob, 4096, 2048, 2048,
                                                   out, nullptr, nullptr, nullptr, nullptr, nullptr);
}